// Round 8
// baseline (51.916 us; speedup 1.0000x reference)
//
#include <hip/hip_runtime.h>

#define BB 4
#define NTOK 2048
#define E 96
#define NH 6
#define DH 16
#define E3 288
#define MSZ (NH*DH*DH)     // 1536 floats per batch
#define SCALE 0.25f        // D^-0.5

// kvT float index: column c (0..191), 4-row chunk starting at row nc (mult of 4);
// stride 36 floats, XOR swizzle permutes 4-row chunks within a column.
__device__ __forceinline__ int KT4(int c, int nc) {
    return c * 36 + (nc ^ ((c & 7) << 2));
}

// ---- K1: per 32-row tile: kv = x@[Wk|Wv]+bias, M-partial quads, atomics ----
__global__ __launch_bounds__(256) void k_kv(const float* __restrict__ x,
                                            const float* __restrict__ Wqkv,
                                            const float* __restrict__ bqkv,
                                            float* __restrict__ Mg) {
    const int b = blockIdx.x >> 6, tile = blockIdx.x & 63;
    const int n0 = tile * 32;
    const int t = threadIdx.x;
    __shared__ float4 xs4[800];       // x tile 32x96, stride 100 floats
    __shared__ float4 wkv4[4704];     // [Wk|Wv] 96x192, stride 196; scratch later
    __shared__ float4 kvT4[1728];     // kvT 192x36 floats (col-major kv, swizzled)
    float* xs = (float*)xs4;
    float* kvT = (float*)kvT4;

    { // stage x: 768 float4
        const float4* src = (const float4*)(x + ((size_t)b * NTOK + n0) * E);
        for (int f = t; f < 768; f += 256) xs4[(f / 24) * 25 + (f % 24)] = src[f];
    }
    { // stage wkv: 4608 float4 (qkv cols 96..287)
        const float4* src = (const float4*)Wqkv;
#pragma unroll
        for (int i = 0; i < 18; i++) {
            int f = t + i * 256;
            int e = f / 48, c = f % 48;
            wkv4[e * 49 + c] = src[e * 72 + 24 + c];
        }
    }
    __syncthreads();

    // kv compute: wave-aligned es-split-4, 8r x 12c register tiles
    const int es = t >> 6;            // wave id = e-split index
    const int tl = t & 63;
    const int rg = tl >> 4, cg = tl & 15;
    const int r0 = rg * 8, c0 = cg * 12;
    float acc[8][12];
#pragma unroll
    for (int i = 0; i < 8; i++)
#pragma unroll
        for (int j = 0; j < 12; j++) acc[i][j] = 0.f;

#pragma unroll
    for (int ch = 0; ch < 3; ch++) {
        const int e0 = es * 24 + ch * 8;
        float4 xr[8][2];
#pragma unroll
        for (int i = 0; i < 8; i++) {
            xr[i][0] = *(const float4*)&xs[(r0 + i) * 100 + e0];
            xr[i][1] = *(const float4*)&xs[(r0 + i) * 100 + e0 + 4];
        }
#pragma unroll
        for (int ee = 0; ee < 8; ee++) {
            const int e = e0 + ee;
            float w[12];
            *(float4*)&w[0] = wkv4[e * 49 + 3 * cg];
            *(float4*)&w[4] = wkv4[e * 49 + 3 * cg + 1];
            *(float4*)&w[8] = wkv4[e * 49 + 3 * cg + 2];
#pragma unroll
            for (int i = 0; i < 8; i++) {
                const float xv = ((const float*)&xr[i][ee >> 2])[ee & 3];
#pragma unroll
                for (int j = 0; j < 12; j++) acc[i][j] += xv * w[j];
            }
        }
    }
    __syncthreads();                  // wkv weight reads done -> scratch reuse

    float4* scratch = wkv4;           // k-major: scratch[(es-1)*1536 + k*64 + tl]
    if (es > 0) {
#pragma unroll
        for (int i = 0; i < 8; i++)
#pragma unroll
            for (int q = 0; q < 3; q++)
                scratch[(es - 1) * 1536 + (i * 3 + q) * 64 + tl] =
                    make_float4(acc[i][q * 4], acc[i][q * 4 + 1], acc[i][q * 4 + 2], acc[i][q * 4 + 3]);
    }
    __syncthreads();
    if (es == 0) {                    // wave0: reduce + bias + transposed kvT write
        float bb[12];
        *(float4*)&bb[0] = *(const float4*)&bqkv[E + c0];
        *(float4*)&bb[4] = *(const float4*)&bqkv[E + c0 + 4];
        *(float4*)&bb[8] = *(const float4*)&bqkv[E + c0 + 8];
#pragma unroll
        for (int s = 0; s < 3; s++)
#pragma unroll
            for (int i = 0; i < 8; i++)
#pragma unroll
                for (int q = 0; q < 3; q++) {
                    const float4 o = scratch[s * 1536 + (i * 3 + q) * 64 + tl];
                    acc[i][q * 4]     += o.x;
                    acc[i][q * 4 + 1] += o.y;
                    acc[i][q * 4 + 2] += o.z;
                    acc[i][q * 4 + 3] += o.w;
                }
#pragma unroll
        for (int i = 0; i < 8; i++)
#pragma unroll
            for (int j = 0; j < 12; j++) acc[i][j] += bb[j];
#pragma unroll
        for (int j = 0; j < 12; j++) {
            const int c = c0 + j;
            *(float4*)&kvT[KT4(c, r0)] =
                make_float4(acc[0][j], acc[1][j], acc[2][j], acc[3][j]);
            *(float4*)&kvT[KT4(c, r0 + 4)] =
                make_float4(acc[4][j], acc[5][j], acc[6][j], acc[7][j]);
        }
    }
    __syncthreads();

    // M phase: thread = (d1,d2) quad {d1,d1+8}x{d2,d2+8}, wave-split over n
    {
        const int ns = es * 8;            // this wave's 8-row n-range
        const int d1 = (t >> 3) & 7, d2 = t & 7;
        float m[NH][4];
#pragma unroll
        for (int h = 0; h < NH; h++)
#pragma unroll
            for (int q = 0; q < 4; q++) m[h][q] = 0.f;
#pragma unroll
        for (int cc = 0; cc < 2; cc++) {
            const int nc = ns + cc * 4;
#pragma unroll
            for (int h = 0; h < NH; h++) {
                const float4 kf0 = *(const float4*)&kvT[KT4(h * 16 + d1, nc)];
                const float4 kf1 = *(const float4*)&kvT[KT4(h * 16 + d1 + 8, nc)];
                const float4 vf0 = *(const float4*)&kvT[KT4(96 + h * 16 + d2, nc)];
                const float4 vf1 = *(const float4*)&kvT[KT4(96 + h * 16 + d2 + 8, nc)];
                m[h][0] += kf0.x * vf0.x + kf0.y * vf0.y + kf0.z * vf0.z + kf0.w * vf0.w;
                m[h][1] += kf0.x * vf1.x + kf0.y * vf1.y + kf0.z * vf1.z + kf0.w * vf1.w;
                m[h][2] += kf1.x * vf0.x + kf1.y * vf0.y + kf1.z * vf0.z + kf1.w * vf0.w;
                m[h][3] += kf1.x * vf1.x + kf1.y * vf1.y + kf1.z * vf1.z + kf1.w * vf1.w;
            }
        }
#pragma unroll
        for (int h = 0; h < NH; h++) {
            float* base = &Mg[b * MSZ + h * 256];
            unsafeAtomicAdd(base + d1 * 16 + d2, m[h][0]);
            unsafeAtomicAdd(base + d1 * 16 + d2 + 8, m[h][1]);
            unsafeAtomicAdd(base + (d1 + 8) * 16 + d2, m[h][2]);
            unsafeAtomicAdd(base + (d1 + 8) * 16 + d2 + 8, m[h][3]);
        }
    }
}

// ---- K2: per 32-row tile: q = x@Wq+bq, t2 = q.BD(SCALE*M), out = t2@Wff+bff --
__global__ __launch_bounds__(256) void k_out(const float* __restrict__ x,
                                             const float* __restrict__ Wqkv,
                                             const float* __restrict__ bqkv,
                                             const float* __restrict__ Wff,
                                             const float* __restrict__ bff,
                                             const float* __restrict__ Mg,
                                             float* __restrict__ out) {
    const int b = blockIdx.x >> 6, tile = blockIdx.x & 63;
    const int n0 = tile * 32;
    const int t = threadIdx.x;
    __shared__ float4 xs4[800];       // x tile; later t2 tile (stride 100)
    __shared__ float4 wbuf4[2400];    // Wq then Wff (96x96, stride 100)
    __shared__ float4 qs4[800];       // q tile (stride 100)
    __shared__ float4 msd4[480];      // Ms2[h][d2][d1], strides 320/20
    __shared__ float4 scratch[2304];  // e-split reduce
    float* xs = (float*)xs4;
    float* qs = (float*)qs4;
    float* Ms2 = (float*)msd4;

    { // stage x
        const float4* src = (const float4*)(x + ((size_t)b * NTOK + n0) * E);
        for (int f = t; f < 768; f += 256) xs4[(f / 24) * 25 + (f % 24)] = src[f];
    }
    { // stage Wq (qkv cols 0..95)
        const float4* src = (const float4*)Wqkv;
#pragma unroll
        for (int i = 0; i < 9; i++) {
            int f = t + i * 256;
            int e = f / 24, c = f % 24;
            wbuf4[e * 25 + c] = src[e * 72 + c];
        }
    }
    { // stage Ms2: [h][d2][d1] (d1-major f4-able), scaled
#pragma unroll
        for (int i = 0; i < 6; i++) {
            const int o = t + i * 256;
            const int h = o >> 8, d1 = (o >> 4) & 15, d2 = o & 15;
            Ms2[h * 320 + d2 * 20 + d1] = SCALE * Mg[b * MSZ + o];
        }
    }
    __syncthreads();

    const int es = t >> 6;            // wave index = e-split-4
    const int tt = t & 63;
    const int rg = tt >> 3, cg = tt & 7;
    const int r0 = rg * 4, c0 = cg * 12;

    float acc[4][12];
    // ---------------- q phase ----------------
#pragma unroll
    for (int i = 0; i < 4; i++)
#pragma unroll
        for (int j = 0; j < 12; j++) acc[i][j] = 0.f;
#pragma unroll
    for (int ch = 0; ch < 3; ch++) {
        const int e0 = es * 24 + ch * 8;
        float4 xr[4][2];
#pragma unroll
        for (int i = 0; i < 4; i++) {
            xr[i][0] = *(const float4*)&xs[(r0 + i) * 100 + e0];
            xr[i][1] = *(const float4*)&xs[(r0 + i) * 100 + e0 + 4];
        }
#pragma unroll
        for (int ee = 0; ee < 8; ee++) {
            const int e = e0 + ee;
            float w[12];
            *(float4*)&w[0] = wbuf4[e * 25 + 3 * cg];
            *(float4*)&w[4] = wbuf4[e * 25 + 3 * cg + 1];
            *(float4*)&w[8] = wbuf4[e * 25 + 3 * cg + 2];
#pragma unroll
            for (int i = 0; i < 4; i++) {
                const float xv = ((const float*)&xr[i][ee >> 2])[ee & 3];
#pragma unroll
                for (int j = 0; j < 12; j++) acc[i][j] += xv * w[j];
            }
        }
    }
    __syncthreads();
    if (es > 0) {
#pragma unroll
        for (int i = 0; i < 4; i++)
#pragma unroll
            for (int q = 0; q < 3; q++)
                scratch[(es - 1) * 768 + (i * 3 + q) * 64 + tt] =
                    make_float4(acc[i][q * 4], acc[i][q * 4 + 1], acc[i][q * 4 + 2], acc[i][q * 4 + 3]);
    }
    __syncthreads();
    if (t < 64) {                     // wave0: reduce + bias -> qs
        float bb[12];
        *(float4*)&bb[0] = *(const float4*)&bqkv[c0];
        *(float4*)&bb[4] = *(const float4*)&bqkv[c0 + 4];
        *(float4*)&bb[8] = *(const float4*)&bqkv[c0 + 8];
#pragma unroll
        for (int s = 0; s < 3; s++)
#pragma unroll
            for (int i = 0; i < 4; i++)
#pragma unroll
                for (int q = 0; q < 3; q++) {
                    const float4 o = scratch[s * 768 + (i * 3 + q) * 64 + tt];
                    acc[i][q * 4]     += o.x;
                    acc[i][q * 4 + 1] += o.y;
                    acc[i][q * 4 + 2] += o.z;
                    acc[i][q * 4 + 3] += o.w;
                }
#pragma unroll
        for (int i = 0; i < 4; i++)
#pragma unroll
            for (int q = 0; q < 3; q++)
                *(float4*)&qs[(r0 + i) * 100 + c0 + q * 4] =
                    make_float4(acc[i][q * 4] + bb[q * 4], acc[i][q * 4 + 1] + bb[q * 4 + 1],
                                acc[i][q * 4 + 2] + bb[q * 4 + 2], acc[i][q * 4 + 3] + bb[q * 4 + 3]);
    } else {                          // waves 1-3: restage wbuf <- Wff
        const float4* src = (const float4*)Wff;
#pragma unroll
        for (int i = 0; i < 12; i++) {
            int f = (t - 64) + i * 192;
            int e = f / 24, c = f % 24;
            wbuf4[e * 25 + c] = src[e * 24 + c];
        }
    }
    __syncthreads();

    // ---------------- t2 phase: t2 = q . BD(Ms) -> xs ----------------
    {
        const int r = t >> 3, tc0 = (t & 7) * 12;
        const int h0 = tc0 >> 4, h1 = (tc0 + 11) >> 4;
        float4 qa[4], qb[4];
#pragma unroll
        for (int u = 0; u < 4; u++) {
            qa[u] = *(const float4*)&qs[r * 100 + h0 * 16 + u * 4];
            qb[u] = *(const float4*)&qs[r * 100 + h1 * 16 + u * 4];
        }
        float t2v[12];
#pragma unroll
        for (int j = 0; j < 12; j++) {
            const int c = tc0 + j, h = c >> 4, d2 = c & 15;
            const float4* mrow = (const float4*)&Ms2[h * 320 + d2 * 20];
            float v = 0.f;
#pragma unroll
            for (int u = 0; u < 4; u++) {
                const float4 qv = (h == h0) ? qa[u] : qb[u];
                const float4 mf = mrow[u];
                v += qv.x * mf.x + qv.y * mf.y + qv.z * mf.z + qv.w * mf.w;
            }
            t2v[j] = v;
        }
        __syncthreads();              // x reads fully done; overwrite with t2
#pragma unroll
        for (int q = 0; q < 3; q++)
            *(float4*)&xs[r * 100 + tc0 + q * 4] =
                make_float4(t2v[q * 4], t2v[q * 4 + 1], t2v[q * 4 + 2], t2v[q * 4 + 3]);
    }
    __syncthreads();

    // ---------------- out phase: out = t2 @ Wff + bff ----------------
#pragma unroll
    for (int i = 0; i < 4; i++)
#pragma unroll
        for (int j = 0; j < 12; j++) acc[i][j] = 0.f;
#pragma unroll
    for (int ch = 0; ch < 3; ch++) {
        const int e0 = es * 24 + ch * 8;
        float4 xr[4][2];
#pragma unroll
        for (int i = 0; i < 4; i++) {
            xr[i][0] = *(const float4*)&xs[(r0 + i) * 100 + e0];
            xr[i][1] = *(const float4*)&xs[(r0 + i) * 100 + e0 + 4];
        }
#pragma unroll
        for (int ee = 0; ee < 8; ee++) {
            const int e = e0 + ee;
            float w[12];
            *(float4*)&w[0] = wbuf4[e * 25 + 3 * cg];
            *(float4*)&w[4] = wbuf4[e * 25 + 3 * cg + 1];
            *(float4*)&w[8] = wbuf4[e * 25 + 3 * cg + 2];
#pragma unroll
            for (int i = 0; i < 4; i++) {
                const float xv = ((const float*)&xr[i][ee >> 2])[ee & 3];
#pragma unroll
                for (int j = 0; j < 12; j++) acc[i][j] += xv * w[j];
            }
        }
    }
    __syncthreads();
    if (es > 0) {
#pragma unroll
        for (int i = 0; i < 4; i++)
#pragma unroll
            for (int q = 0; q < 3; q++)
                scratch[(es - 1) * 768 + (i * 3 + q) * 64 + tt] =
                    make_float4(acc[i][q * 4], acc[i][q * 4 + 1], acc[i][q * 4 + 2], acc[i][q * 4 + 3]);
    }
    __syncthreads();
    if (t < 64) {                     // wave0: reduce + bff + global store
        float bb[12];
        *(float4*)&bb[0] = *(const float4*)&bff[c0];
        *(float4*)&bb[4] = *(const float4*)&bff[c0 + 4];
        *(float4*)&bb[8] = *(const float4*)&bff[c0 + 8];
#pragma unroll
        for (int s = 0; s < 3; s++)
#pragma unroll
            for (int i = 0; i < 4; i++)
#pragma unroll
                for (int q = 0; q < 3; q++) {
                    const float4 o = scratch[s * 768 + (i * 3 + q) * 64 + tt];
                    acc[i][q * 4]     += o.x;
                    acc[i][q * 4 + 1] += o.y;
                    acc[i][q * 4 + 2] += o.z;
                    acc[i][q * 4 + 3] += o.w;
                }
#pragma unroll
        for (int i = 0; i < 4; i++) {
            float* orow = out + ((size_t)b * NTOK + n0 + r0 + i) * E + c0;
#pragma unroll
            for (int q = 0; q < 3; q++)
                *(float4*)&orow[q * 4] =
                    make_float4(acc[i][q * 4] + bb[q * 4], acc[i][q * 4 + 1] + bb[q * 4 + 1],
                                acc[i][q * 4 + 2] + bb[q * 4 + 2], acc[i][q * 4 + 3] + bb[q * 4 + 3]);
        }
    }
}

extern "C" void kernel_launch(void* const* d_in, const int* in_sizes, int n_in,
                              void* d_out, int out_size, void* d_ws, size_t ws_size,
                              hipStream_t stream) {
    const float* x    = (const float*)d_in[0];
    const float* Wqkv = (const float*)d_in[1];
    const float* bqkv = (const float*)d_in[2];
    const float* Wff  = (const float*)d_in[3];
    const float* bff  = (const float*)d_in[4];
    float* out = (float*)d_out;
    float* Mg  = (float*)d_ws;                     // BB * 1536 floats

    hipMemsetAsync(Mg, 0, (size_t)BB * MSZ * sizeof(float), stream);
    k_kv<<<BB * 64, 256, 0, stream>>>(x, Wqkv, bqkv, Mg);
    k_out<<<BB * 64, 256, 0, stream>>>(x, Wqkv, bqkv, Wff, bff, Mg, out);
}

// Round 9
// 22.767 us; speedup vs baseline: 2.2804x; 2.2804x over previous
//
#include <hip/hip_runtime.h>

#define BB 4
#define NTOK 2048
#define E 96
#define NH 6
#define E3 288
#define MSZ 1536           // 6*16*16 floats per batch
#define SCALE 0.25f        // D^-0.5

typedef __attribute__((ext_vector_type(8))) short bf16x8;
typedef __attribute__((ext_vector_type(4))) float f32x4;

__device__ __forceinline__ short f2bf(float f) {   // RNE f32 -> bf16
    unsigned u = __float_as_uint(f);
    u += 0x7fff + ((u >> 16) & 1);
    return (short)(u >> 16);
}

// ---- K1: per 32-row tile: kv = x@[Wk|Wv]+bias (bf16 MFMA), M_h = K_h^T V_h
// ----     (one MFMA per head), unsafeAtomicAdd into Mg[b]
__global__ __launch_bounds__(256) void k_kv(const float* __restrict__ x,
                                            const float* __restrict__ Wqkv,
                                            const float* __restrict__ bqkv,
                                            float* __restrict__ Mg) {
    const int b = blockIdx.x >> 6, tile = blockIdx.x & 63;
    const int n0 = tile * 32;
    const int t = threadIdx.x;
    __shared__ short xb[32 * 104];     // x tile bf16, [n][e], stride 104
    __shared__ short wkvT[192 * 104];  // [Wk|Wv]^T bf16: [c][e], stride 104
    __shared__ short kvn[192 * 40];    // kv^T bf16: [feat][n], stride 40

    { // stage x -> bf16
        const float4* src = (const float4*)(x + ((size_t)b * NTOK + n0) * E);
        for (int f = t; f < 768; f += 256) {
            float4 v = src[f];
            int r = f / 24, c4 = (f % 24) * 4;
            short4 s = { f2bf(v.x), f2bf(v.y), f2bf(v.z), f2bf(v.w) };
            *(short4*)&xb[r * 104 + c4] = s;
        }
    }
    { // stage W[k|v]^T -> bf16, transposed (e-pairs -> short2 writes)
        for (int f = t; f < 2304; f += 256) {
            int ep = f / 48, cq = (f % 48) * 4;
            const float4 a = *(const float4*)(Wqkv + (size_t)(2 * ep) * E3 + E + cq);
            const float4 c = *(const float4*)(Wqkv + (size_t)(2 * ep + 1) * E3 + E + cq);
            *(short2*)&wkvT[(cq + 0) * 104 + 2 * ep] = make_short2(f2bf(a.x), f2bf(c.x));
            *(short2*)&wkvT[(cq + 1) * 104 + 2 * ep] = make_short2(f2bf(a.y), f2bf(c.y));
            *(short2*)&wkvT[(cq + 2) * 104 + 2 * ep] = make_short2(f2bf(a.z), f2bf(c.z));
            *(short2*)&wkvT[(cq + 3) * 104 + 2 * ep] = make_short2(f2bf(a.w), f2bf(c.w));
        }
    }
    __syncthreads();

    const int w = t >> 6, lane = t & 63;
    const int rhalf = w & 1, chalf = w >> 1;    // rows 16*rhalf, cols 96*chalf
    const int lr = lane & 15, kg = lane >> 4;

    { // kv MFMA: each wave 6 C-tiles (16x16) x 3 K-steps
        f32x4 acc[6];
#pragma unroll
        for (int j = 0; j < 6; j++) acc[j] = (f32x4){0.f, 0.f, 0.f, 0.f};
#pragma unroll
        for (int ks = 0; ks < 3; ks++) {
            const bf16x8 af = *(const bf16x8*)&xb[(rhalf * 16 + lr) * 104 + ks * 32 + kg * 8];
#pragma unroll
            for (int j = 0; j < 6; j++) {
                const bf16x8 bf = *(const bf16x8*)&wkvT[(chalf * 96 + j * 16 + lr) * 104 + ks * 32 + kg * 8];
                acc[j] = __builtin_amdgcn_mfma_f32_16x16x32_bf16(af, bf, acc[j], 0, 0, 0);
            }
        }
        // bias (f32) then round once to bf16, write kv^T [feat][n]
        const int nr = rhalf * 16 + kg * 4;
#pragma unroll
        for (int j = 0; j < 6; j++) {
            const int cg = chalf * 96 + j * 16 + lr;
            const float bias = bqkv[E + cg];
            short4 s = { f2bf(acc[j][0] + bias), f2bf(acc[j][1] + bias),
                         f2bf(acc[j][2] + bias), f2bf(acc[j][3] + bias) };
            *(short4*)&kvn[cg * 40 + nr] = s;
        }
    }
    __syncthreads();

    { // M phase: head h -> one 16x16x32 MFMA (K = 32 tokens), then atomics
        for (int h = w; h < NH; h += 4) {
            const bf16x8 ka = *(const bf16x8*)&kvn[(h * 16 + lr) * 40 + kg * 8];
            const bf16x8 vb = *(const bf16x8*)&kvn[(96 + h * 16 + lr) * 40 + kg * 8];
            f32x4 mc = (f32x4){0.f, 0.f, 0.f, 0.f};
            mc = __builtin_amdgcn_mfma_f32_16x16x32_bf16(ka, vb, mc, 0, 0, 0);
            float* base = &Mg[b * MSZ + h * 256];
            const int d2 = lr, d1b = kg * 4;
            unsafeAtomicAdd(base + (d1b + 0) * 16 + d2, mc[0]);
            unsafeAtomicAdd(base + (d1b + 1) * 16 + d2, mc[1]);
            unsafeAtomicAdd(base + (d1b + 2) * 16 + d2, mc[2]);
            unsafeAtomicAdd(base + (d1b + 3) * 16 + d2, mc[3]);
        }
    }
}

// ---- K2: per 32-row tile: q = x@Wq+bq (MFMA), t2 = q.BD(SCALE*M) (f32 VALU),
// ----     out = t2@Wff + bff (MFMA)
__global__ __launch_bounds__(256) void k_out(const float* __restrict__ x,
                                             const float* __restrict__ Wqkv,
                                             const float* __restrict__ bqkv,
                                             const float* __restrict__ Wff,
                                             const float* __restrict__ bff,
                                             const float* __restrict__ Mg,
                                             float* __restrict__ out) {
    const int b = blockIdx.x >> 6, tile = blockIdx.x & 63;
    const int n0 = tile * 32;
    const int t = threadIdx.x;
    __shared__ short xb[32 * 104];     // x tile bf16
    __shared__ short wT[96 * 104];     // Wq^T then Wff^T, bf16 [c][e]
    __shared__ short t2b[32 * 104];    // t2 bf16 [n][e]
    __shared__ float qs[32 * 100];     // q f32 [n][col], stride 100
    __shared__ float Ms2[NH * 320];    // SCALE*M, [h][d2*20 + d1]

    { // stage x -> bf16
        const float4* src = (const float4*)(x + ((size_t)b * NTOK + n0) * E);
        for (int f = t; f < 768; f += 256) {
            float4 v = src[f];
            int r = f / 24, c4 = (f % 24) * 4;
            short4 s = { f2bf(v.x), f2bf(v.y), f2bf(v.z), f2bf(v.w) };
            *(short4*)&xb[r * 104 + c4] = s;
        }
    }
    { // stage Wq^T -> bf16
        for (int f = t; f < 1152; f += 256) {
            int ep = f / 24, cq = (f % 24) * 4;
            const float4 a = *(const float4*)(Wqkv + (size_t)(2 * ep) * E3 + cq);
            const float4 c = *(const float4*)(Wqkv + (size_t)(2 * ep + 1) * E3 + cq);
            *(short2*)&wT[(cq + 0) * 104 + 2 * ep] = make_short2(f2bf(a.x), f2bf(c.x));
            *(short2*)&wT[(cq + 1) * 104 + 2 * ep] = make_short2(f2bf(a.y), f2bf(c.y));
            *(short2*)&wT[(cq + 2) * 104 + 2 * ep] = make_short2(f2bf(a.z), f2bf(c.z));
            *(short2*)&wT[(cq + 3) * 104 + 2 * ep] = make_short2(f2bf(a.w), f2bf(c.w));
        }
    }
    { // stage Ms2 (f32, scaled): [h][d2][d1] padded 20
#pragma unroll
        for (int i = 0; i < 6; i++) {
            const int o = t + i * 256;
            const int h = o >> 8, d1 = (o >> 4) & 15, d2 = o & 15;
            Ms2[h * 320 + d2 * 20 + d1] = SCALE * Mg[b * MSZ + o];
        }
    }
    __syncthreads();

    const int w = t >> 6, lane = t & 63;
    const int rhalf = w & 1, chalf = w >> 1;    // rows 16*rhalf, cols 48*chalf
    const int lr = lane & 15, kg = lane >> 4;
    const int nr = rhalf * 16 + kg * 4;

    { // q MFMA: each wave 3 C-tiles x 3 K-steps; +bias -> qs (f32)
        f32x4 acc[3];
#pragma unroll
        for (int j = 0; j < 3; j++) acc[j] = (f32x4){0.f, 0.f, 0.f, 0.f};
#pragma unroll
        for (int ks = 0; ks < 3; ks++) {
            const bf16x8 af = *(const bf16x8*)&xb[(rhalf * 16 + lr) * 104 + ks * 32 + kg * 8];
#pragma unroll
            for (int j = 0; j < 3; j++) {
                const bf16x8 bf = *(const bf16x8*)&wT[(chalf * 48 + j * 16 + lr) * 104 + ks * 32 + kg * 8];
                acc[j] = __builtin_amdgcn_mfma_f32_16x16x32_bf16(af, bf, acc[j], 0, 0, 0);
            }
        }
#pragma unroll
        for (int j = 0; j < 3; j++) {
            const int col = chalf * 48 + j * 16 + lr;
            const float bq = bqkv[col];
            qs[(nr + 0) * 100 + col] = acc[j][0] + bq;
            qs[(nr + 1) * 100 + col] = acc[j][1] + bq;
            qs[(nr + 2) * 100 + col] = acc[j][2] + bq;
            qs[(nr + 3) * 100 + col] = acc[j][3] + bq;
        }
    }
    __syncthreads();

    { // restage wT <- Wff^T (issue global loads first), then t2 (f32 VALU)
        for (int f = t; f < 1152; f += 256) {
            int ep = f / 24, cq = (f % 24) * 4;
            const float4 a = *(const float4*)(Wff + (size_t)(2 * ep) * E + cq);
            const float4 c = *(const float4*)(Wff + (size_t)(2 * ep + 1) * E + cq);
            *(short2*)&wT[(cq + 0) * 104 + 2 * ep] = make_short2(f2bf(a.x), f2bf(c.x));
            *(short2*)&wT[(cq + 1) * 104 + 2 * ep] = make_short2(f2bf(a.y), f2bf(c.y));
            *(short2*)&wT[(cq + 2) * 104 + 2 * ep] = make_short2(f2bf(a.z), f2bf(c.z));
            *(short2*)&wT[(cq + 3) * 104 + 2 * ep] = make_short2(f2bf(a.w), f2bf(c.w));
        }
        // t2 = q . BD(Ms)  (R6-proven phase, output rounded to bf16)
        const int r = t >> 3, tc0 = (t & 7) * 12;
        const int h0 = tc0 >> 4, h1 = (tc0 + 11) >> 4;
        float4 qa[4], qb[4];
#pragma unroll
        for (int u = 0; u < 4; u++) {
            qa[u] = *(const float4*)&qs[r * 100 + h0 * 16 + u * 4];
            qb[u] = *(const float4*)&qs[r * 100 + h1 * 16 + u * 4];
        }
        float t2v[12];
#pragma unroll
        for (int j = 0; j < 12; j++) {
            const int c = tc0 + j, h = c >> 4, d2 = c & 15;
            const float4* mrow = (const float4*)&Ms2[h * 320 + d2 * 20];
            float v = 0.f;
#pragma unroll
            for (int u = 0; u < 4; u++) {
                const float4 qv = (h == h0) ? qa[u] : qb[u];
                const float4 mf = mrow[u];
                v += qv.x * mf.x + qv.y * mf.y + qv.z * mf.z + qv.w * mf.w;
            }
            t2v[j] = v;
        }
#pragma unroll
        for (int q3 = 0; q3 < 3; q3++) {
            short4 s = { f2bf(t2v[q3 * 4]), f2bf(t2v[q3 * 4 + 1]),
                         f2bf(t2v[q3 * 4 + 2]), f2bf(t2v[q3 * 4 + 3]) };
            *(short4*)&t2b[r * 104 + tc0 + q3 * 4] = s;
        }
    }
    __syncthreads();

    { // out MFMA: 3 C-tiles x 3 K-steps; +bff; coalesced-ish f32 stores
        f32x4 acc[3];
#pragma unroll
        for (int j = 0; j < 3; j++) acc[j] = (f32x4){0.f, 0.f, 0.f, 0.f};
#pragma unroll
        for (int ks = 0; ks < 3; ks++) {
            const bf16x8 af = *(const bf16x8*)&t2b[(rhalf * 16 + lr) * 104 + ks * 32 + kg * 8];
#pragma unroll
            for (int j = 0; j < 3; j++) {
                const bf16x8 bf = *(const bf16x8*)&wT[(chalf * 48 + j * 16 + lr) * 104 + ks * 32 + kg * 8];
                acc[j] = __builtin_amdgcn_mfma_f32_16x16x32_bf16(af, bf, acc[j], 0, 0, 0);
            }
        }
        float* obase = out + ((size_t)b * NTOK + n0 + nr) * E;
#pragma unroll
        for (int j = 0; j < 3; j++) {
            const int col = chalf * 48 + j * 16 + lr;
            const float bv = bff[col];
            obase[0 * E + col] = acc[j][0] + bv;
            obase[1 * E + col] = acc[j][1] + bv;
            obase[2 * E + col] = acc[j][2] + bv;
            obase[3 * E + col] = acc[j][3] + bv;
        }
    }
}

extern "C" void kernel_launch(void* const* d_in, const int* in_sizes, int n_in,
                              void* d_out, int out_size, void* d_ws, size_t ws_size,
                              hipStream_t stream) {
    const float* x    = (const float*)d_in[0];
    const float* Wqkv = (const float*)d_in[1];
    const float* bqkv = (const float*)d_in[2];
    const float* Wff  = (const float*)d_in[3];
    const float* bff  = (const float*)d_in[4];
    float* out = (float*)d_out;
    float* Mg  = (float*)d_ws;                     // BB * 1536 floats

    hipMemsetAsync(Mg, 0, (size_t)BB * MSZ * sizeof(float), stream);
    k_kv<<<BB * 64, 256, 0, stream>>>(x, Wqkv, bqkv, Mg);
    k_out<<<BB * 64, 256, 0, stream>>>(x, Wqkv, bqkv, Wff, bff, Mg, out);
}

// Round 10
// 19.704 us; speedup vs baseline: 2.6348x; 1.1554x over previous
//
#include <hip/hip_runtime.h>
#include <hip/hip_bf16.h>

#define BB 4
#define NTOK 2048
#define E 96
#define NH 6
#define E3 288
#define MSZ 1536           // 6*16*16 per (batch,tile) partial
#define SCALE 0.25f        // D^-0.5

typedef __attribute__((ext_vector_type(8))) short bf16x8;
typedef __attribute__((ext_vector_type(4))) float f32x4;

__device__ __forceinline__ short f2bf(float f) {   // RNE via compiler cvt
    __hip_bfloat16 h = __float2bfloat16(f);
    return __builtin_bit_cast(short, h);
}

// ---- K1: per 32-row tile: kv = x@[Wk|Wv]+bias (bf16 MFMA), M-partial per head
// ----     via one MFMA, stored as bf16 partials (no atomics, no memset)
__global__ __launch_bounds__(256) void k_kv(const float* __restrict__ x,
                                            const float* __restrict__ Wqkv,
                                            const float* __restrict__ bqkv,
                                            short* __restrict__ Mp) {
    const int L = ((blockIdx.x & 7) << 5) | (blockIdx.x >> 3);   // XCD-chunked
    const int b = L >> 6, tile = L & 63;
    const int n0 = tile * 32;
    const int t = threadIdx.x;
    __shared__ short xb[32 * 104];     // x tile bf16, [n][e], stride 104
    __shared__ short wkvT[192 * 104];  // [Wk|Wv]^T bf16: [c][e], stride 104
    __shared__ short kvn[192 * 40];    // kv^T bf16: [feat][n], stride 40

    { // stage x -> bf16
        const float4* src = (const float4*)(x + ((size_t)b * NTOK + n0) * E);
        for (int f = t; f < 768; f += 256) {
            float4 v = src[f];
            int r = f / 24, c4 = (f % 24) * 4;
            short4 s = { f2bf(v.x), f2bf(v.y), f2bf(v.z), f2bf(v.w) };
            *(short4*)&xb[r * 104 + c4] = s;
        }
    }
    { // stage W[k|v]^T -> bf16, transposed (e-pairs -> short2 writes)
        for (int f = t; f < 2304; f += 256) {
            int ep = f / 48, cq = (f % 48) * 4;
            const float4 a = *(const float4*)(Wqkv + (size_t)(2 * ep) * E3 + E + cq);
            const float4 c = *(const float4*)(Wqkv + (size_t)(2 * ep + 1) * E3 + E + cq);
            *(short2*)&wkvT[(cq + 0) * 104 + 2 * ep] = make_short2(f2bf(a.x), f2bf(c.x));
            *(short2*)&wkvT[(cq + 1) * 104 + 2 * ep] = make_short2(f2bf(a.y), f2bf(c.y));
            *(short2*)&wkvT[(cq + 2) * 104 + 2 * ep] = make_short2(f2bf(a.z), f2bf(c.z));
            *(short2*)&wkvT[(cq + 3) * 104 + 2 * ep] = make_short2(f2bf(a.w), f2bf(c.w));
        }
    }
    __syncthreads();

    const int w = t >> 6, lane = t & 63;
    const int rhalf = w & 1, chalf = w >> 1;    // rows 16*rhalf, cols 96*chalf
    const int lr = lane & 15, kg = lane >> 4;

    { // kv MFMA: each wave 6 C-tiles (16x16) x 3 K-steps
        f32x4 acc[6];
#pragma unroll
        for (int j = 0; j < 6; j++) acc[j] = (f32x4){0.f, 0.f, 0.f, 0.f};
#pragma unroll
        for (int ks = 0; ks < 3; ks++) {
            const bf16x8 af = *(const bf16x8*)&xb[(rhalf * 16 + lr) * 104 + ks * 32 + kg * 8];
#pragma unroll
            for (int j = 0; j < 6; j++) {
                const bf16x8 bf = *(const bf16x8*)&wkvT[(chalf * 96 + j * 16 + lr) * 104 + ks * 32 + kg * 8];
                acc[j] = __builtin_amdgcn_mfma_f32_16x16x32_bf16(af, bf, acc[j], 0, 0, 0);
            }
        }
        // bias (f32) then round once to bf16, write kv^T [feat][n]
        const int nr = rhalf * 16 + kg * 4;
#pragma unroll
        for (int j = 0; j < 6; j++) {
            const int cg = chalf * 96 + j * 16 + lr;
            const float bias = bqkv[E + cg];
            short4 s = { f2bf(acc[j][0] + bias), f2bf(acc[j][1] + bias),
                         f2bf(acc[j][2] + bias), f2bf(acc[j][3] + bias) };
            *(short4*)&kvn[cg * 40 + nr] = s;
        }
    }
    __syncthreads();

    { // M phase: head h -> one 16x16x32 MFMA (K = 32 tokens), bf16 partial store
        short* mpt = Mp + (size_t)L * MSZ;
        for (int h = w; h < NH; h += 4) {
            const bf16x8 ka = *(const bf16x8*)&kvn[(h * 16 + lr) * 40 + kg * 8];
            const bf16x8 vb = *(const bf16x8*)&kvn[(96 + h * 16 + lr) * 40 + kg * 8];
            f32x4 mc = (f32x4){0.f, 0.f, 0.f, 0.f};
            mc = __builtin_amdgcn_mfma_f32_16x16x32_bf16(ka, vb, mc, 0, 0, 0);
            // element o = h*256 + lane*4 + i  <->  M[h][d1=kg*4+i][d2=lr]
            short4 s = { f2bf(mc[0]), f2bf(mc[1]), f2bf(mc[2]), f2bf(mc[3]) };
            *(short4*)&mpt[h * 256 + lane * 4] = s;
        }
    }
}

// ---- K2: reduce M partials (bf16, 64 tiles) -> Ms2; q = x@Wq+bq (MFMA);
// ----     t2 = q.BD(SCALE*M) (f32 VALU); out = t2@Wff + bff (MFMA)
__global__ __launch_bounds__(256) void k_out(const float* __restrict__ x,
                                             const float* __restrict__ Wqkv,
                                             const float* __restrict__ bqkv,
                                             const float* __restrict__ Wff,
                                             const float* __restrict__ bff,
                                             const short* __restrict__ Mp,
                                             float* __restrict__ out) {
    const int L = ((blockIdx.x & 7) << 5) | (blockIdx.x >> 3);   // XCD-chunked
    const int b = L >> 6, tile = L & 63;
    const int n0 = tile * 32;
    const int t = threadIdx.x;
    __shared__ short xb[32 * 104];     // x tile bf16
    __shared__ short wT[96 * 104];     // Wq^T then Wff^T, bf16 [c][e]
    __shared__ short t2b[32 * 104];    // t2 bf16 [n][e]
    __shared__ float qs[32 * 100];     // q f32 [n][col], stride 100
    __shared__ float Ms2[NH * 320];    // SCALE*M, [h][d2*20 + d1]

    { // stage x -> bf16
        const float4* src = (const float4*)(x + ((size_t)b * NTOK + n0) * E);
        for (int f = t; f < 768; f += 256) {
            float4 v = src[f];
            int r = f / 24, c4 = (f % 24) * 4;
            short4 s = { f2bf(v.x), f2bf(v.y), f2bf(v.z), f2bf(v.w) };
            *(short4*)&xb[r * 104 + c4] = s;
        }
    }
    { // stage Wq^T -> bf16
        for (int f = t; f < 1152; f += 256) {
            int ep = f / 24, cq = (f % 24) * 4;
            const float4 a = *(const float4*)(Wqkv + (size_t)(2 * ep) * E3 + cq);
            const float4 c = *(const float4*)(Wqkv + (size_t)(2 * ep + 1) * E3 + cq);
            *(short2*)&wT[(cq + 0) * 104 + 2 * ep] = make_short2(f2bf(a.x), f2bf(c.x));
            *(short2*)&wT[(cq + 1) * 104 + 2 * ep] = make_short2(f2bf(a.y), f2bf(c.y));
            *(short2*)&wT[(cq + 2) * 104 + 2 * ep] = make_short2(f2bf(a.z), f2bf(c.z));
            *(short2*)&wT[(cq + 3) * 104 + 2 * ep] = make_short2(f2bf(a.w), f2bf(c.w));
        }
    }
    { // reduce 64 bf16 partials -> Ms2 (threads 0..191, 8 elements each)
        if (t < 192) {
            float racc[8];
#pragma unroll
            for (int j = 0; j < 8; j++) racc[j] = 0.f;
            const short* mpb = Mp + (size_t)b * 64 * MSZ + t * 8;
#pragma unroll 8
            for (int tl = 0; tl < 64; ++tl) {
                const bf16x8 v = *(const bf16x8*)(mpb + (size_t)tl * MSZ);
#pragma unroll
                for (int j = 0; j < 8; j++)
                    racc[j] += __uint_as_float(((unsigned)(unsigned short)v[j]) << 16);
            }
#pragma unroll
            for (int j = 0; j < 8; j++) {
                const int o = t * 8 + j;
                const int h = o >> 8, kg = (o >> 6) & 3, lr = (o >> 2) & 15, i = o & 3;
                Ms2[h * 320 + lr * 20 + kg * 4 + i] = SCALE * racc[j];
            }
        }
    }
    __syncthreads();

    const int w = t >> 6, lane = t & 63;
    const int rhalf = w & 1, chalf = w >> 1;    // rows 16*rhalf, cols 48*chalf
    const int lr = lane & 15, kg = lane >> 4;
    const int nr = rhalf * 16 + kg * 4;

    { // q MFMA: each wave 3 C-tiles x 3 K-steps; +bias -> qs (f32)
        f32x4 acc[3];
#pragma unroll
        for (int j = 0; j < 3; j++) acc[j] = (f32x4){0.f, 0.f, 0.f, 0.f};
#pragma unroll
        for (int ks = 0; ks < 3; ks++) {
            const bf16x8 af = *(const bf16x8*)&xb[(rhalf * 16 + lr) * 104 + ks * 32 + kg * 8];
#pragma unroll
            for (int j = 0; j < 3; j++) {
                const bf16x8 bf = *(const bf16x8*)&wT[(chalf * 48 + j * 16 + lr) * 104 + ks * 32 + kg * 8];
                acc[j] = __builtin_amdgcn_mfma_f32_16x16x32_bf16(af, bf, acc[j], 0, 0, 0);
            }
        }
#pragma unroll
        for (int j = 0; j < 3; j++) {
            const int col = chalf * 48 + j * 16 + lr;
            const float bq = bqkv[col];
            qs[(nr + 0) * 100 + col] = acc[j][0] + bq;
            qs[(nr + 1) * 100 + col] = acc[j][1] + bq;
            qs[(nr + 2) * 100 + col] = acc[j][2] + bq;
            qs[(nr + 3) * 100 + col] = acc[j][3] + bq;
        }
    }
    __syncthreads();

    { // restage wT <- Wff^T, then t2 = q.BD(Ms2) (f32 VALU) -> t2b bf16
        for (int f = t; f < 1152; f += 256) {
            int ep = f / 24, cq = (f % 24) * 4;
            const float4 a = *(const float4*)(Wff + (size_t)(2 * ep) * E + cq);
            const float4 c = *(const float4*)(Wff + (size_t)(2 * ep + 1) * E + cq);
            *(short2*)&wT[(cq + 0) * 104 + 2 * ep] = make_short2(f2bf(a.x), f2bf(c.x));
            *(short2*)&wT[(cq + 1) * 104 + 2 * ep] = make_short2(f2bf(a.y), f2bf(c.y));
            *(short2*)&wT[(cq + 2) * 104 + 2 * ep] = make_short2(f2bf(a.z), f2bf(c.z));
            *(short2*)&wT[(cq + 3) * 104 + 2 * ep] = make_short2(f2bf(a.w), f2bf(c.w));
        }
        const int r = t >> 3, tc0 = (t & 7) * 12;
        const int h0 = tc0 >> 4, h1 = (tc0 + 11) >> 4;
        float4 qa[4], qb[4];
#pragma unroll
        for (int u = 0; u < 4; u++) {
            qa[u] = *(const float4*)&qs[r * 100 + h0 * 16 + u * 4];
            qb[u] = *(const float4*)&qs[r * 100 + h1 * 16 + u * 4];
        }
        float t2v[12];
#pragma unroll
        for (int j = 0; j < 12; j++) {
            const int c = tc0 + j, h = c >> 4, d2 = c & 15;
            const float4* mrow = (const float4*)&Ms2[h * 320 + d2 * 20];
            float v = 0.f;
#pragma unroll
            for (int u = 0; u < 4; u++) {
                const float4 qv = (h == h0) ? qa[u] : qb[u];
                const float4 mf = mrow[u];
                v += qv.x * mf.x + qv.y * mf.y + qv.z * mf.z + qv.w * mf.w;
            }
            t2v[j] = v;
        }
#pragma unroll
        for (int q3 = 0; q3 < 3; q3++) {
            short4 s = { f2bf(t2v[q3 * 4]), f2bf(t2v[q3 * 4 + 1]),
                         f2bf(t2v[q3 * 4 + 2]), f2bf(t2v[q3 * 4 + 3]) };
            *(short4*)&t2b[r * 104 + tc0 + q3 * 4] = s;
        }
    }
    __syncthreads();

    { // out MFMA: 3 C-tiles x 3 K-steps; +bff; f32 stores
        f32x4 acc[3];
#pragma unroll
        for (int j = 0; j < 3; j++) acc[j] = (f32x4){0.f, 0.f, 0.f, 0.f};
#pragma unroll
        for (int ks = 0; ks < 3; ks++) {
            const bf16x8 af = *(const bf16x8*)&t2b[(rhalf * 16 + lr) * 104 + ks * 32 + kg * 8];
#pragma unroll
            for (int j = 0; j < 3; j++) {
                const bf16x8 bf = *(const bf16x8*)&wT[(chalf * 48 + j * 16 + lr) * 104 + ks * 32 + kg * 8];
                acc[j] = __builtin_amdgcn_mfma_f32_16x16x32_bf16(af, bf, acc[j], 0, 0, 0);
            }
        }
        float* obase = out + ((size_t)b * NTOK + n0 + nr) * E;
#pragma unroll
        for (int j = 0; j < 3; j++) {
            const int col = chalf * 48 + j * 16 + lr;
            const float bv = bff[col];
            obase[0 * E + col] = acc[j][0] + bv;
            obase[1 * E + col] = acc[j][1] + bv;
            obase[2 * E + col] = acc[j][2] + bv;
            obase[3 * E + col] = acc[j][3] + bv;
        }
    }
}

extern "C" void kernel_launch(void* const* d_in, const int* in_sizes, int n_in,
                              void* d_out, int out_size, void* d_ws, size_t ws_size,
                              hipStream_t stream) {
    const float* x    = (const float*)d_in[0];
    const float* Wqkv = (const float*)d_in[1];
    const float* bqkv = (const float*)d_in[2];
    const float* Wff  = (const float*)d_in[3];
    const float* bff  = (const float*)d_in[4];
    float* out = (float*)d_out;
    short* Mp  = (short*)d_ws;                     // BB*64*MSZ bf16 partials

    k_kv<<<BB * 64, 256, 0, stream>>>(x, Wqkv, bqkv, Mp);
    k_out<<<BB * 64, 256, 0, stream>>>(x, Wqkv, bqkv, Wff, bff, Mp, out);
}